// Round 1
// baseline (611.799 us; speedup 1.0000x reference)
//
#include <hip/hip_runtime.h>

#define N_NODES 50000
#define N_EDGES 800000

// ---------- ordered-uint encoding for float atomicMax ----------
__device__ __forceinline__ unsigned fenc(float f) {
  unsigned b = __float_as_uint(f);
  return (b & 0x80000000u) ? ~b : (b | 0x80000000u);
}
__device__ __forceinline__ float fdec(unsigned u) {
  unsigned b = (u & 0x80000000u) ? (u ^ 0x80000000u) : ~u;
  return __uint_as_float(b);
}

// ---------- pass 1: per-edge scores + segment max ----------
__global__ __launch_bounds__(256) void k_edge_score(
    const float* __restrict__ x, const int* __restrict__ ei,
    const float* __restrict__ ea,
    const float* __restrict__ Wl, const float* __restrict__ bl,
    const float* __restrict__ Wr, const float* __restrict__ br,
    const float* __restrict__ We, const float* __restrict__ att,
    float* __restrict__ score, unsigned* __restrict__ smax)
{
  int e = blockIdx.x * 256 + threadIdx.x;
  if (e >= N_EDGES) return;
  int s = ei[e], d = ei[N_EDGES + e];
  float x0s = x[2*s], x1s = x[2*s+1];
  float x0d = x[2*d], x1d = x[2*d+1];
  float av = ea[e];

  float s0 = 0.f, s1 = 0.f;
  #pragma unroll 8
  for (int k = 0; k < 64; ++k) {
    float m = bl[k] + br[k];
    m = fmaf(x0s, Wl[k], m);
    m = fmaf(x1s, Wl[128+k], m);
    m = fmaf(x0d, Wr[k], m);
    m = fmaf(x1d, Wr[128+k], m);
    m = fmaf(av, We[k], m);
    float l = m > 0.f ? m : 0.2f * m;
    s0 = fmaf(l, att[k], s0);
  }
  #pragma unroll 8
  for (int k = 64; k < 128; ++k) {
    float m = bl[k] + br[k];
    m = fmaf(x0s, Wl[k], m);
    m = fmaf(x1s, Wl[128+k], m);
    m = fmaf(x0d, Wr[k], m);
    m = fmaf(x1d, Wr[128+k], m);
    m = fmaf(av, We[k], m);
    float l = m > 0.f ? m : 0.2f * m;
    s1 = fmaf(l, att[k], s1);
  }
  score[2*e]   = s0;
  score[2*e+1] = s1;
  atomicMax(&smax[2*d],   fenc(s0));
  atomicMax(&smax[2*d+1], fenc(s1));
}

// ---------- pass 2: exp + segment sums (denom, A0, A1) ----------
__global__ __launch_bounds__(256) void k_edge_accum(
    const float* __restrict__ x, const int* __restrict__ ei,
    const float* __restrict__ score, const unsigned* __restrict__ smax,
    float* __restrict__ denom, float* __restrict__ A0, float* __restrict__ A1)
{
  int e = blockIdx.x * 256 + threadIdx.x;
  if (e >= N_EDGES) return;
  int s = ei[e], d = ei[N_EDGES + e];
  float x0s = x[2*s], x1s = x[2*s+1];
  #pragma unroll
  for (int hh = 0; hh < 2; ++hh) {
    float sc = score[2*e+hh];
    float mx = fdec(smax[2*d+hh]);
    float ex = __expf(sc - mx);
    atomicAdd(&denom[2*d+hh], ex);
    atomicAdd(&A0[2*d+hh], ex * x0s);
    atomicAdd(&A1[2*d+hh], ex * x1s);
  }
}

// ---------- pass 3: per-node h = relu(out + bias), factored ----------
__global__ __launch_bounds__(256) void k_node_h(
    const float* __restrict__ denom, const float* __restrict__ A0,
    const float* __restrict__ A1,
    const float* __restrict__ Wl, const float* __restrict__ bl,
    const float* __restrict__ bias,
    float* __restrict__ hbuf)
{
  int idx = blockIdx.x * 256 + threadIdx.x;
  if (idx >= N_NODES * 128) return;
  int n = idx >> 7, k = idx & 127, hh = k >> 6;
  float D = denom[2*n+hh];
  float r = 1.0f / (D + 1e-16f);
  float v = A0[2*n+hh]*r*Wl[k] + A1[2*n+hh]*r*Wl[128+k] + D*r*bl[k] + bias[k];
  hbuf[idx] = v > 0.f ? v : 0.f;
}

// ---------- pass 4: msg_emb = msg @ Wfc + bfc (512 unique rows) ----------
__global__ __launch_bounds__(128) void k_fc(
    const float* __restrict__ msg, const float* __restrict__ Wfc,
    const float* __restrict__ bfc, float* __restrict__ me)
{
  int j = blockIdx.x, k = threadIdx.x;
  __shared__ float mrow[128];
  mrow[k] = msg[j*128 + k];
  __syncthreads();
  float acc = bfc[k];
  #pragma unroll 8
  for (int t = 0; t < 128; ++t) acc = fmaf(mrow[t], Wfc[t*128 + k], acc);
  me[j*128 + k] = acc;
}

// ---------- pass 5: dot = h @ me^T, 64x64 tiles; fused column max ----------
__global__ __launch_bounds__(256) void k_gemm(
    const float* __restrict__ hbuf, const float* __restrict__ me,
    float* __restrict__ dout, unsigned* __restrict__ colmax)
{
  __shared__ float As[64*65];
  __shared__ float Bs[64*65];
  __shared__ float Red[16*64];
  int n0 = blockIdx.x * 64, c0 = blockIdx.y * 64;
  int tid = threadIdx.x;
  int tr = tid >> 4, tc = tid & 15;

  float acc[4][4] = {{0.f}};

  for (int kt = 0; kt < 2; ++kt) {
    #pragma unroll
    for (int q = 0; q < 4; ++q) {
      int lin = tid + q * 256;          // 0..1023 float4 slots
      int r = lin >> 4;                 // 16 float4 per 64-float row
      int kq = (lin & 15) << 2;
      int gk = kt * 64 + kq;
      float4 va = make_float4(0.f, 0.f, 0.f, 0.f);
      int gr = n0 + r;
      if (gr < N_NODES) va = *(const float4*)&hbuf[(size_t)gr*128 + gk];
      As[r*65 + kq + 0] = va.x; As[r*65 + kq + 1] = va.y;
      As[r*65 + kq + 2] = va.z; As[r*65 + kq + 3] = va.w;
      float4 vb = *(const float4*)&me[(size_t)(c0 + r)*128 + gk];
      Bs[r*65 + kq + 0] = vb.x; Bs[r*65 + kq + 1] = vb.y;
      Bs[r*65 + kq + 2] = vb.z; Bs[r*65 + kq + 3] = vb.w;
    }
    __syncthreads();
    #pragma unroll 4
    for (int k = 0; k < 64; ++k) {
      float a0 = As[(tr*4+0)*65 + k];
      float a1 = As[(tr*4+1)*65 + k];
      float a2 = As[(tr*4+2)*65 + k];
      float a3 = As[(tr*4+3)*65 + k];
      float b0 = Bs[(tc*4+0)*65 + k];
      float b1 = Bs[(tc*4+1)*65 + k];
      float b2 = Bs[(tc*4+2)*65 + k];
      float b3 = Bs[(tc*4+3)*65 + k];
      acc[0][0] = fmaf(a0,b0,acc[0][0]); acc[0][1] = fmaf(a0,b1,acc[0][1]);
      acc[0][2] = fmaf(a0,b2,acc[0][2]); acc[0][3] = fmaf(a0,b3,acc[0][3]);
      acc[1][0] = fmaf(a1,b0,acc[1][0]); acc[1][1] = fmaf(a1,b1,acc[1][1]);
      acc[1][2] = fmaf(a1,b2,acc[1][2]); acc[1][3] = fmaf(a1,b3,acc[1][3]);
      acc[2][0] = fmaf(a2,b0,acc[2][0]); acc[2][1] = fmaf(a2,b1,acc[2][1]);
      acc[2][2] = fmaf(a2,b2,acc[2][2]); acc[2][3] = fmaf(a2,b3,acc[2][3]);
      acc[3][0] = fmaf(a3,b0,acc[3][0]); acc[3][1] = fmaf(a3,b1,acc[3][1]);
      acc[3][2] = fmaf(a3,b2,acc[3][2]); acc[3][3] = fmaf(a3,b3,acc[3][3]);
    }
    __syncthreads();
  }

  // store dot into first 512 columns of d_out
  int rbase = n0 + tr*4, cbase = c0 + tc*4;
  #pragma unroll
  for (int i = 0; i < 4; ++i) {
    if (rbase + i < N_NODES) {
      #pragma unroll
      for (int j = 0; j < 4; ++j)
        dout[(size_t)(rbase+i)*1024 + cbase + j] = acc[i][j];
    }
  }

  // fused per-column max (zero-padded rows contribute 0 -> safe shift)
  #pragma unroll
  for (int j = 0; j < 4; ++j) {
    float m = fmaxf(fmaxf(acc[0][j], acc[1][j]), fmaxf(acc[2][j], acc[3][j]));
    Red[tr*64 + tc*4 + j] = m;
  }
  __syncthreads();
  if (tid < 64) {
    float v = Red[tid];
    #pragma unroll
    for (int rr = 1; rr < 16; ++rr) v = fmaxf(v, Red[rr*64 + tid]);
    atomicMax(&colmax[c0 + tid], fenc(v));
  }
}

// ---------- pass 6: column sums of exp(dot - max) ----------
__global__ __launch_bounds__(512) void k_colsum(
    const float* __restrict__ dout, const unsigned* __restrict__ colmax,
    float* __restrict__ colsum)
{
  int j = threadIdx.x;  // 0..511
  float M = fdec(colmax[j]);
  int r0 = blockIdx.x * 256;
  int r1 = r0 + 256; if (r1 > N_NODES) r1 = N_NODES;
  float acc = 0.f;
  for (int n = r0; n < r1; ++n)
    acc += __expf(dout[(size_t)n*1024 + j] - M);
  atomicAdd(&colsum[j], acc);
}

// ---------- pass 7: normalize + duplicate columns ----------
__global__ __launch_bounds__(256) void k_final(
    float* __restrict__ dout, const unsigned* __restrict__ colmax,
    const float* __restrict__ colsum)
{
  int n = blockIdx.x;
  #pragma unroll
  for (int q = 0; q < 2; ++q) {
    int jj = threadIdx.x + q*256;
    float M = fdec(colmax[jj]);
    float S = colsum[jj];
    float v = dout[(size_t)n*1024 + jj];
    float o = __expf(v - M) / S;
    dout[(size_t)n*1024 + jj] = o;
    dout[(size_t)n*1024 + 512 + jj] = o;
  }
}

extern "C" void kernel_launch(void* const* d_in, const int* in_sizes, int n_in,
                              void* d_out, int out_size, void* d_ws, size_t ws_size,
                              hipStream_t stream)
{
  const float* message = (const float*)d_in[0];
  const float* x       = (const float*)d_in[1];
  const int*   ei      = (const int*)d_in[2];
  const float* ea      = (const float*)d_in[3];
  // conv1 params (d_in[4..10]) are dead code in the reference
  const float* Wl2   = (const float*)d_in[11];
  const float* bl2   = (const float*)d_in[12];
  const float* Wr2   = (const float*)d_in[13];
  const float* br2   = (const float*)d_in[14];
  const float* We2   = (const float*)d_in[15];
  const float* att2  = (const float*)d_in[16];
  const float* bias2 = (const float*)d_in[17];
  const float* Wfc   = (const float*)d_in[18];
  const float* bfc   = (const float*)d_in[19];

  float* ws    = (float*)d_ws;
  float* hbuf  = ws;                                   // N*128
  float* score = hbuf + (size_t)N_NODES * 128;         // E*2
  float* me    = score + (size_t)N_EDGES * 2;          // 512*128
  float* acc0  = me + 512 * 128;                       // zeroed accumulators:
  unsigned* smax  = (unsigned*)acc0;                   //   N*2 u32
  float* denom    = acc0 + N_NODES * 2;                //   N*2
  float* A0       = denom + N_NODES * 2;               //   N*2
  float* A1       = A0 + N_NODES * 2;                  //   N*2
  unsigned* colmax = (unsigned*)(A1 + N_NODES * 2);    //   512 u32
  float* colsum    = (float*)(colmax + 512);           //   512
  size_t accBytes = (size_t)(N_NODES * 2 * 4 + 1024) * sizeof(float);
  hipMemsetAsync(acc0, 0, accBytes, stream);

  float* dout = (float*)d_out;

  k_edge_score<<<(N_EDGES + 255) / 256, 256, 0, stream>>>(
      x, ei, ea, Wl2, bl2, Wr2, br2, We2, att2, score, smax);
  k_edge_accum<<<(N_EDGES + 255) / 256, 256, 0, stream>>>(
      x, ei, score, smax, denom, A0, A1);
  k_node_h<<<(N_NODES * 128 + 255) / 256, 256, 0, stream>>>(
      denom, A0, A1, Wl2, bl2, bias2, hbuf);
  k_fc<<<512, 128, 0, stream>>>(message, Wfc, bfc, me);
  dim3 gg((N_NODES + 63) / 64, 8);
  k_gemm<<<gg, 256, 0, stream>>>(hbuf, me, dout, colmax);
  k_colsum<<<(N_NODES + 255) / 256, 512, 0, stream>>>(dout, colmax, colsum);
  k_final<<<N_NODES, 256, 0, stream>>>(dout, colmax, colsum);
}

// Round 2
// 442.398 us; speedup vs baseline: 1.3829x; 1.3829x over previous
//
#include <hip/hip_runtime.h>

#define N_NODES 50000
#define N_EDGES 800000

// ---------- pass 1: histogram of dst ----------
__global__ __launch_bounds__(256) void k_hist(
    const int* __restrict__ ei, int* __restrict__ cnt)
{
  int e = blockIdx.x * 256 + threadIdx.x;
  if (e >= N_EDGES) return;
  atomicAdd(&cnt[ei[N_EDGES + e]], 1);
}

// ---------- pass 2: exclusive prefix scan (single block) ----------
__global__ __launch_bounds__(1024) void k_scan(
    const int* __restrict__ cnt, int* __restrict__ offs, int* __restrict__ cursor)
{
  __shared__ int part[1024];
  int t = threadIdx.x;
  const int CH = (N_NODES + 1023) / 1024;  // 49
  int lo = t * CH, hi = lo + CH;
  if (hi > N_NODES) hi = N_NODES;
  int s = 0;
  for (int i = lo; i < hi; ++i) s += cnt[i];
  part[t] = s;
  __syncthreads();
  for (int off = 1; off < 1024; off <<= 1) {
    int v = (t >= off) ? part[t - off] : 0;
    __syncthreads();
    part[t] += v;
    __syncthreads();
  }
  int run = (t == 0) ? 0 : part[t - 1];
  for (int i = lo; i < hi; ++i) {
    offs[i] = run; cursor[i] = run; run += cnt[i];
  }
  if (t == 1023) offs[N_NODES] = part[1023];
}

// ---------- pass 3: fused score + scatter by dst ----------
__global__ __launch_bounds__(256) void k_scatter(
    const float* __restrict__ x, const int* __restrict__ ei,
    const float* __restrict__ ea,
    const float* __restrict__ Wl, const float* __restrict__ bl,
    const float* __restrict__ Wr, const float* __restrict__ br,
    const float* __restrict__ We, const float* __restrict__ att,
    int* __restrict__ cursor, float4* __restrict__ rec)
{
  int e = blockIdx.x * 256 + threadIdx.x;
  if (e >= N_EDGES) return;
  int s = ei[e], d = ei[N_EDGES + e];
  float x0s = x[2*s], x1s = x[2*s+1];
  float x0d = x[2*d], x1d = x[2*d+1];
  float av = ea[e];

  float s0 = 0.f, s1 = 0.f;
  #pragma unroll 8
  for (int k = 0; k < 64; ++k) {
    float m = bl[k] + br[k];
    m = fmaf(x0s, Wl[k], m);
    m = fmaf(x1s, Wl[128+k], m);
    m = fmaf(x0d, Wr[k], m);
    m = fmaf(x1d, Wr[128+k], m);
    m = fmaf(av, We[k], m);
    float l = m > 0.f ? m : 0.2f * m;
    s0 = fmaf(l, att[k], s0);
  }
  #pragma unroll 8
  for (int k = 64; k < 128; ++k) {
    float m = bl[k] + br[k];
    m = fmaf(x0s, Wl[k], m);
    m = fmaf(x1s, Wl[128+k], m);
    m = fmaf(x0d, Wr[k], m);
    m = fmaf(x1d, Wr[128+k], m);
    m = fmaf(av, We[k], m);
    float l = m > 0.f ? m : 0.2f * m;
    s1 = fmaf(l, att[k], s1);
  }
  int pos = atomicAdd(&cursor[d], 1);
  rec[pos] = make_float4(s0, s1, x0s, x1s);
}

// ---------- pass 4: per-node gather reduction (no atomics) ----------
__global__ __launch_bounds__(256) void k_gather(
    const float4* __restrict__ rec, const int* __restrict__ offs,
    float* __restrict__ nodeF)
{
  int n = blockIdx.x * 256 + threadIdx.x;
  if (n >= N_NODES) return;
  int a = offs[n], b = offs[n + 1];
  float m0 = 0.f, m1 = 0.f;
  if (b > a) {
    m0 = -1e30f; m1 = -1e30f;
    for (int i = a; i < b; ++i) {
      float4 r = rec[i];
      m0 = fmaxf(m0, r.x);
      m1 = fmaxf(m1, r.y);
    }
  }
  float D0 = 0.f, A00 = 0.f, A10 = 0.f;
  float D1 = 0.f, A01 = 0.f, A11 = 0.f;
  for (int i = a; i < b; ++i) {
    float4 r = rec[i];
    float e0 = __expf(r.x - m0);
    float e1 = __expf(r.y - m1);
    D0 += e0; A00 += e0 * r.z; A10 += e0 * r.w;
    D1 += e1; A01 += e1 * r.z; A11 += e1 * r.w;
  }
  float* nf = nodeF + (size_t)n * 8;
  nf[0] = D0; nf[1] = A00; nf[2] = A10;
  nf[3] = D1; nf[4] = A01; nf[5] = A11;
}

// ---------- pass 5: per-node h = relu(out + bias), factored ----------
__global__ __launch_bounds__(256) void k_node_h(
    const float* __restrict__ nodeF,
    const float* __restrict__ Wl, const float* __restrict__ bl,
    const float* __restrict__ bias,
    float* __restrict__ hbuf)
{
  int idx = blockIdx.x * 256 + threadIdx.x;
  if (idx >= N_NODES * 128) return;
  int n = idx >> 7, k = idx & 127, hh = k >> 6;
  const float* nf = nodeF + (size_t)n * 8 + hh * 3;
  float D = nf[0], A0 = nf[1], A1 = nf[2];
  float r = 1.0f / (D + 1e-16f);
  float v = A0*r*Wl[k] + A1*r*Wl[128+k] + D*r*bl[k] + bias[k];
  hbuf[idx] = v > 0.f ? v : 0.f;
}

// ---------- pass 6: msg_emb = msg @ Wfc + bfc ----------
__global__ __launch_bounds__(128) void k_fc(
    const float* __restrict__ msg, const float* __restrict__ Wfc,
    const float* __restrict__ bfc, float* __restrict__ me)
{
  int j = blockIdx.x, k = threadIdx.x;
  __shared__ float mrow[128];
  mrow[k] = msg[j*128 + k];
  __syncthreads();
  float acc = bfc[k];
  #pragma unroll 8
  for (int t = 0; t < 128; ++t) acc = fmaf(mrow[t], Wfc[t*128 + k], acc);
  me[j*128 + k] = acc;
}

// ---------- pass 7: dot GEMM; store exp(dot); fused column sums ----------
__global__ __launch_bounds__(256) void k_gemm(
    const float* __restrict__ hbuf, const float* __restrict__ me,
    float* __restrict__ dout, float* __restrict__ colsum)
{
  __shared__ float As[64*65];
  __shared__ float Bs[64*65];
  __shared__ float Red[16*64];
  int n0 = blockIdx.x * 64, c0 = blockIdx.y * 64;
  int tid = threadIdx.x;
  int tr = tid >> 4, tc = tid & 15;

  float acc[4][4] = {{0.f}};

  for (int kt = 0; kt < 2; ++kt) {
    #pragma unroll
    for (int q = 0; q < 4; ++q) {
      int lin = tid + q * 256;
      int r = lin >> 4;
      int kq = (lin & 15) << 2;
      int gk = kt * 64 + kq;
      float4 va = make_float4(0.f, 0.f, 0.f, 0.f);
      int gr = n0 + r;
      if (gr < N_NODES) va = *(const float4*)&hbuf[(size_t)gr*128 + gk];
      As[r*65 + kq + 0] = va.x; As[r*65 + kq + 1] = va.y;
      As[r*65 + kq + 2] = va.z; As[r*65 + kq + 3] = va.w;
      float4 vb = *(const float4*)&me[(size_t)(c0 + r)*128 + gk];
      Bs[r*65 + kq + 0] = vb.x; Bs[r*65 + kq + 1] = vb.y;
      Bs[r*65 + kq + 2] = vb.z; Bs[r*65 + kq + 3] = vb.w;
    }
    __syncthreads();
    #pragma unroll 4
    for (int k = 0; k < 64; ++k) {
      float a0 = As[(tr*4+0)*65 + k];
      float a1 = As[(tr*4+1)*65 + k];
      float a2 = As[(tr*4+2)*65 + k];
      float a3 = As[(tr*4+3)*65 + k];
      float b0 = Bs[(tc*4+0)*65 + k];
      float b1 = Bs[(tc*4+1)*65 + k];
      float b2 = Bs[(tc*4+2)*65 + k];
      float b3 = Bs[(tc*4+3)*65 + k];
      acc[0][0] = fmaf(a0,b0,acc[0][0]); acc[0][1] = fmaf(a0,b1,acc[0][1]);
      acc[0][2] = fmaf(a0,b2,acc[0][2]); acc[0][3] = fmaf(a0,b3,acc[0][3]);
      acc[1][0] = fmaf(a1,b0,acc[1][0]); acc[1][1] = fmaf(a1,b1,acc[1][1]);
      acc[1][2] = fmaf(a1,b2,acc[1][2]); acc[1][3] = fmaf(a1,b3,acc[1][3]);
      acc[2][0] = fmaf(a2,b0,acc[2][0]); acc[2][1] = fmaf(a2,b1,acc[2][1]);
      acc[2][2] = fmaf(a2,b2,acc[2][2]); acc[2][3] = fmaf(a2,b3,acc[2][3]);
      acc[3][0] = fmaf(a3,b0,acc[3][0]); acc[3][1] = fmaf(a3,b1,acc[3][1]);
      acc[3][2] = fmaf(a3,b2,acc[3][2]); acc[3][3] = fmaf(a3,b3,acc[3][3]);
    }
    __syncthreads();
  }

  // epilogue: ex = exp(dot) (no max; |dot| is small), store + column partials
  int rbase = n0 + tr*4, cbase = c0 + tc*4;
  float ex[4][4];
  #pragma unroll
  for (int i = 0; i < 4; ++i) {
    bool valid = (rbase + i) < N_NODES;
    #pragma unroll
    for (int j = 0; j < 4; ++j)
      ex[i][j] = valid ? __expf(acc[i][j]) : 0.f;
    if (valid) {
      #pragma unroll
      for (int j = 0; j < 4; ++j)
        dout[(size_t)(rbase+i)*1024 + cbase + j] = ex[i][j];
    }
  }
  #pragma unroll
  for (int j = 0; j < 4; ++j)
    Red[tr*64 + tc*4 + j] = ex[0][j] + ex[1][j] + ex[2][j] + ex[3][j];
  __syncthreads();
  if (tid < 64) {
    float v = Red[tid];
    #pragma unroll
    for (int rr = 1; rr < 16; ++rr) v += Red[rr*64 + tid];
    atomicAdd(&colsum[c0 + tid], v);
  }
}

// ---------- pass 8: normalize + duplicate columns ----------
__global__ __launch_bounds__(256) void k_final(
    float* __restrict__ dout, const float* __restrict__ colsum)
{
  int n0 = blockIdx.x * 4;
  int c = threadIdx.x * 2;
  float2 S = *(const float2*)&colsum[c];
  float r0 = 1.0f / S.x, r1 = 1.0f / S.y;
  #pragma unroll
  for (int rr = 0; rr < 4; ++rr) {
    size_t base = (size_t)(n0 + rr) * 1024;
    float2 v = *(const float2*)&dout[base + c];
    v.x *= r0; v.y *= r1;
    *(float2*)&dout[base + c] = v;
    *(float2*)&dout[base + 512 + c] = v;
  }
}

extern "C" void kernel_launch(void* const* d_in, const int* in_sizes, int n_in,
                              void* d_out, int out_size, void* d_ws, size_t ws_size,
                              hipStream_t stream)
{
  const float* message = (const float*)d_in[0];
  const float* x       = (const float*)d_in[1];
  const int*   ei      = (const int*)d_in[2];
  const float* ea      = (const float*)d_in[3];
  // conv1 params (d_in[4..10]) are dead code in the reference
  const float* Wl2   = (const float*)d_in[11];
  const float* bl2   = (const float*)d_in[12];
  const float* Wr2   = (const float*)d_in[13];
  const float* br2   = (const float*)d_in[14];
  const float* We2   = (const float*)d_in[15];
  const float* att2  = (const float*)d_in[16];
  const float* bias2 = (const float*)d_in[17];
  const float* Wfc   = (const float*)d_in[18];
  const float* bfc   = (const float*)d_in[19];

  float* ws   = (float*)d_ws;
  float*  hbuf  = ws;                                      // N*128
  float4* rec   = (float4*)(hbuf + (size_t)N_NODES * 128); // E float4
  float*  me    = (float*)(rec + N_EDGES);                 // 512*128
  float*  nodeF = me + 512 * 128;                          // N*8
  int*    cnt   = (int*)(nodeF + (size_t)N_NODES * 8);     // N      (zeroed)
  float*  colsum= (float*)(cnt + N_NODES);                 // 512    (zeroed)
  int*    offs  = (int*)(colsum + 512);                    // N+1
  int*    cursor= offs + N_NODES + 1;                      // N

  hipMemsetAsync(cnt, 0, (N_NODES + 512) * sizeof(int), stream);

  float* dout = (float*)d_out;

  k_hist<<<(N_EDGES + 255) / 256, 256, 0, stream>>>(ei, cnt);
  k_scan<<<1, 1024, 0, stream>>>(cnt, offs, cursor);
  k_scatter<<<(N_EDGES + 255) / 256, 256, 0, stream>>>(
      x, ei, ea, Wl2, bl2, Wr2, br2, We2, att2, cursor, rec);
  k_gather<<<(N_NODES + 255) / 256, 256, 0, stream>>>(rec, offs, nodeF);
  k_node_h<<<(N_NODES * 128 + 255) / 256, 256, 0, stream>>>(
      nodeF, Wl2, bl2, bias2, hbuf);
  k_fc<<<512, 128, 0, stream>>>(message, Wfc, bfc, me);
  dim3 gg((N_NODES + 63) / 64, 8);
  k_gemm<<<gg, 256, 0, stream>>>(hbuf, me, dout, colsum);
  k_final<<<N_NODES / 4, 256, 0, stream>>>(dout, colsum);
}

// Round 3
// 399.500 us; speedup vs baseline: 1.5314x; 1.1074x over previous
//
#include <hip/hip_runtime.h>
#include <hip/hip_bf16.h>

#define N_NODES 50000
#define N_PAD   50048          // 782 * 64
#define N_EDGES 800000

typedef __attribute__((ext_vector_type(8))) short short8;
typedef __attribute__((ext_vector_type(4))) float f32x4;

// ---------- pass 1: histogram of dst ----------
__global__ __launch_bounds__(256) void k_hist(
    const int* __restrict__ ei, int* __restrict__ cnt)
{
  int e = blockIdx.x * 256 + threadIdx.x;
  if (e >= N_EDGES) return;
  atomicAdd(&cnt[ei[N_EDGES + e]], 1);
}

// ---------- pass 2: exclusive prefix scan (single block) ----------
__global__ __launch_bounds__(1024) void k_scan(
    const int* __restrict__ cnt, int* __restrict__ offs, int* __restrict__ cursor)
{
  __shared__ int part[1024];
  int t = threadIdx.x;
  const int CH = (N_NODES + 1023) / 1024;
  int lo = t * CH, hi = lo + CH;
  if (hi > N_NODES) hi = N_NODES;
  int s = 0;
  for (int i = lo; i < hi; ++i) s += cnt[i];
  part[t] = s;
  __syncthreads();
  for (int off = 1; off < 1024; off <<= 1) {
    int v = (t >= off) ? part[t - off] : 0;
    __syncthreads();
    part[t] += v;
    __syncthreads();
  }
  int run = (t == 0) ? 0 : part[t - 1];
  for (int i = lo; i < hi; ++i) {
    offs[i] = run; cursor[i] = run; run += cnt[i];
  }
  if (t == 1023) offs[N_NODES] = part[1023];
}

// ---------- pass 3: fused score + scatter by dst ----------
__global__ __launch_bounds__(256) void k_scatter(
    const float* __restrict__ x, const int* __restrict__ ei,
    const float* __restrict__ ea,
    const float* __restrict__ Wl, const float* __restrict__ bl,
    const float* __restrict__ Wr, const float* __restrict__ br,
    const float* __restrict__ We, const float* __restrict__ att,
    int* __restrict__ cursor, float4* __restrict__ rec)
{
  int e = blockIdx.x * 256 + threadIdx.x;
  if (e >= N_EDGES) return;
  int s = ei[e], d = ei[N_EDGES + e];
  float x0s = x[2*s], x1s = x[2*s+1];
  float x0d = x[2*d], x1d = x[2*d+1];
  float av = ea[e];

  float s0 = 0.f, s1 = 0.f;
  #pragma unroll 8
  for (int k = 0; k < 64; ++k) {
    float m = bl[k] + br[k];
    m = fmaf(x0s, Wl[k], m);
    m = fmaf(x1s, Wl[128+k], m);
    m = fmaf(x0d, Wr[k], m);
    m = fmaf(x1d, Wr[128+k], m);
    m = fmaf(av, We[k], m);
    float l = m > 0.f ? m : 0.2f * m;
    s0 = fmaf(l, att[k], s0);
  }
  #pragma unroll 8
  for (int k = 64; k < 128; ++k) {
    float m = bl[k] + br[k];
    m = fmaf(x0s, Wl[k], m);
    m = fmaf(x1s, Wl[128+k], m);
    m = fmaf(x0d, Wr[k], m);
    m = fmaf(x1d, Wr[128+k], m);
    m = fmaf(av, We[k], m);
    float l = m > 0.f ? m : 0.2f * m;
    s1 = fmaf(l, att[k], s1);
  }
  int pos = atomicAdd(&cursor[d], 1);
  rec[pos] = make_float4(s0, s1, x0s, x1s);
}

// ---------- pass 4: per-node gather reduction (no atomics) ----------
__global__ __launch_bounds__(256) void k_gather(
    const float4* __restrict__ rec, const int* __restrict__ offs,
    float* __restrict__ nodeF)
{
  int n = blockIdx.x * 256 + threadIdx.x;
  if (n >= N_NODES) return;
  int a = offs[n], b = offs[n + 1];
  float m0 = 0.f, m1 = 0.f;
  if (b > a) {
    m0 = -1e30f; m1 = -1e30f;
    for (int i = a; i < b; ++i) {
      float4 r = rec[i];
      m0 = fmaxf(m0, r.x);
      m1 = fmaxf(m1, r.y);
    }
  }
  float D0 = 0.f, A00 = 0.f, A10 = 0.f;
  float D1 = 0.f, A01 = 0.f, A11 = 0.f;
  for (int i = a; i < b; ++i) {
    float4 r = rec[i];
    float e0 = __expf(r.x - m0);
    float e1 = __expf(r.y - m1);
    D0 += e0; A00 += e0 * r.z; A10 += e0 * r.w;
    D1 += e1; A01 += e1 * r.z; A11 += e1 * r.w;
  }
  float* nf = nodeF + (size_t)n * 8;
  nf[0] = D0; nf[1] = A00; nf[2] = A10;
  nf[3] = D1; nf[4] = A01; nf[5] = A11;
}

// ---------- pass 5: per-node h (factored) -> bf16 hi/lo ----------
__global__ __launch_bounds__(256) void k_node_h(
    const float* __restrict__ nodeF,
    const float* __restrict__ Wl, const float* __restrict__ bl,
    const float* __restrict__ bias,
    __hip_bfloat16* __restrict__ h_hi, __hip_bfloat16* __restrict__ h_lo)
{
  int idx = blockIdx.x * 256 + threadIdx.x;
  if (idx >= N_PAD * 128) return;
  int n = idx >> 7, k = idx & 127;
  float v = 0.f;
  if (n < N_NODES) {
    int hh = k >> 6;
    const float* nf = nodeF + (size_t)n * 8 + hh * 3;
    float D = nf[0], A0 = nf[1], A1 = nf[2];
    float r = 1.0f / (D + 1e-16f);
    v = A0*r*Wl[k] + A1*r*Wl[128+k] + D*r*bl[k] + bias[k];
    v = v > 0.f ? v : 0.f;
  }
  __hip_bfloat16 hi = __float2bfloat16(v);
  float rem = v - __bfloat162float(hi);
  h_hi[idx] = hi;
  h_lo[idx] = __float2bfloat16(rem);
}

// ---------- pass 6: msg_emb -> bf16 hi/lo ----------
__global__ __launch_bounds__(128) void k_fc(
    const float* __restrict__ msg, const float* __restrict__ Wfc,
    const float* __restrict__ bfc,
    __hip_bfloat16* __restrict__ me_hi, __hip_bfloat16* __restrict__ me_lo)
{
  int j = blockIdx.x, k = threadIdx.x;
  __shared__ float mrow[128];
  mrow[k] = msg[j*128 + k];
  __syncthreads();
  float acc = bfc[k];
  #pragma unroll 8
  for (int t = 0; t < 128; ++t) acc = fmaf(mrow[t], Wfc[t*128 + k], acc);
  __hip_bfloat16 hi = __float2bfloat16(acc);
  me_hi[j*128 + k] = hi;
  me_lo[j*128 + k] = __float2bfloat16(acc - __bfloat162float(hi));
}

// ---------- pass 7/8: split-bf16 MFMA GEMM ----------
// Block: 256 threads = 4 waves; tile = 64 rows x (loop over 8 col-blocks of 64).
// Wave w owns col strip w*16..w*16+15 and all 64 rows (4 row-tiles).
// A-frags (h rows) in registers, loaded once. B (me cols) staged reg->LDS,
// kg-major slot layout: slot = kg*64 + col (kg = k/8), conflict-free b128 reads.
// WRITE=0: colsum accumulation only. WRITE=1: normalize + store both halves.
template<int WRITE>
__global__ __launch_bounds__(256) void k_mfma(
    const __hip_bfloat16* __restrict__ h_hi, const __hip_bfloat16* __restrict__ h_lo,
    const __hip_bfloat16* __restrict__ me_hi, const __hip_bfloat16* __restrict__ me_lo,
    float* __restrict__ colsum, float* __restrict__ dout)
{
  __shared__ short8 Bt[2048];   // 32 KB: [0..1023]=hi, [1024..2047]=lo
  int tid = threadIdx.x;
  int lane = tid & 63, w = tid >> 6;
  int g = lane >> 4, c = lane & 15;
  int m0 = blockIdx.x * 64;

  // A fragments: a[rt][ks] covers row m0+rt*16+c, k = ks*32 + g*8 .. +8
  short8 a_hi[4][4], a_lo[4][4];
  #pragma unroll
  for (int rt = 0; rt < 4; ++rt) {
    size_t rowb = (size_t)(m0 + rt*16 + c) * 128 + g*8;
    #pragma unroll
    for (int ks = 0; ks < 4; ++ks) {
      a_hi[rt][ks] = *(const short8*)(h_hi + rowb + ks*32);
      a_lo[rt][ks] = *(const short8*)(h_lo + rowb + ks*32);
    }
  }

  short8 sreg[8];
  // issue loads for col-block 0
  #pragma unroll
  for (int q = 0; q < 8; ++q) {
    int slot = q * 256 + tid;
    int s = slot & 1023;
    int col = s & 63, kg = s >> 6;
    const __hip_bfloat16* src = (slot < 1024) ? me_hi : me_lo;
    sreg[q] = *(const short8*)(src + (size_t)col * 128 + kg*8);
  }

  for (int cb = 0; cb < 8; ++cb) {
    // write staged B to LDS
    #pragma unroll
    for (int q = 0; q < 8; ++q) Bt[q * 256 + tid] = sreg[q];
    // prefetch next col-block
    if (cb + 1 < 8) {
      #pragma unroll
      for (int q = 0; q < 8; ++q) {
        int slot = q * 256 + tid;
        int s = slot & 1023;
        int col = s & 63, kg = s >> 6;
        const __hip_bfloat16* src = (slot < 1024) ? me_hi : me_lo;
        sreg[q] = *(const short8*)(src + (size_t)((cb + 1) * 64 + col) * 128 + kg*8);
      }
    }
    __syncthreads();

    f32x4 acc[4] = {f32x4{0,0,0,0}, f32x4{0,0,0,0}, f32x4{0,0,0,0}, f32x4{0,0,0,0}};
    #pragma unroll
    for (int ks = 0; ks < 4; ++ks) {
      short8 bh = Bt[(ks*4 + g) * 64 + w*16 + c];
      short8 bl = Bt[1024 + (ks*4 + g) * 64 + w*16 + c];
      #pragma unroll
      for (int rt = 0; rt < 4; ++rt) {
        acc[rt] = __builtin_amdgcn_mfma_f32_16x16x32_bf16(a_hi[rt][ks], bh, acc[rt], 0, 0, 0);
        acc[rt] = __builtin_amdgcn_mfma_f32_16x16x32_bf16(a_lo[rt][ks], bh, acc[rt], 0, 0, 0);
        acc[rt] = __builtin_amdgcn_mfma_f32_16x16x32_bf16(a_hi[rt][ks], bl, acc[rt], 0, 0, 0);
      }
    }
    __syncthreads();   // all waves done reading Bt before next overwrite

    int col = cb * 64 + w * 16 + c;
    if (WRITE == 0) {
      float csum = 0.f;
      #pragma unroll
      for (int rt = 0; rt < 4; ++rt) {
        #pragma unroll
        for (int r = 0; r < 4; ++r) {
          int row = m0 + rt*16 + g*4 + r;
          csum += (row < N_NODES) ? __expf(acc[rt][r]) : 0.f;
        }
      }
      csum += __shfl_xor(csum, 16);
      csum += __shfl_xor(csum, 32);
      if (lane < 16) atomicAdd(&colsum[cb * 64 + w * 16 + lane], csum);
    } else {
      float S = colsum[col];
      float rS = 1.0f / S;
      #pragma unroll
      for (int rt = 0; rt < 4; ++rt) {
        #pragma unroll
        for (int r = 0; r < 4; ++r) {
          int row = m0 + rt*16 + g*4 + r;
          if (row < N_NODES) {
            float o = __expf(acc[rt][r]) * rS;
            dout[(size_t)row * 1024 + col] = o;
            dout[(size_t)row * 1024 + 512 + col] = o;
          }
        }
      }
    }
  }
}

extern "C" void kernel_launch(void* const* d_in, const int* in_sizes, int n_in,
                              void* d_out, int out_size, void* d_ws, size_t ws_size,
                              hipStream_t stream)
{
  const float* message = (const float*)d_in[0];
  const float* x       = (const float*)d_in[1];
  const int*   ei      = (const int*)d_in[2];
  const float* ea      = (const float*)d_in[3];
  // conv1 params (d_in[4..10]) are dead code in the reference
  const float* Wl2   = (const float*)d_in[11];
  const float* bl2   = (const float*)d_in[12];
  const float* Wr2   = (const float*)d_in[13];
  const float* br2   = (const float*)d_in[14];
  const float* We2   = (const float*)d_in[15];
  const float* att2  = (const float*)d_in[16];
  const float* bias2 = (const float*)d_in[17];
  const float* Wfc   = (const float*)d_in[18];
  const float* bfc   = (const float*)d_in[19];

  char* p = (char*)d_ws;
  float4* rec = (float4*)p;                 p += (size_t)N_EDGES * 16;
  float* nodeF = (float*)p;                 p += (size_t)N_NODES * 8 * 4;
  __hip_bfloat16* h_hi = (__hip_bfloat16*)p; p += (size_t)N_PAD * 128 * 2;
  __hip_bfloat16* h_lo = (__hip_bfloat16*)p; p += (size_t)N_PAD * 128 * 2;
  __hip_bfloat16* me_hi = (__hip_bfloat16*)p; p += 512 * 128 * 2;
  __hip_bfloat16* me_lo = (__hip_bfloat16*)p; p += 512 * 128 * 2;
  int* cnt = (int*)p;                       p += (size_t)N_NODES * 4;
  float* colsum = (float*)p;                p += 512 * 4;
  int* offs = (int*)p;                      p += (size_t)(N_NODES + 1) * 4;
  int* cursor = (int*)p;

  hipMemsetAsync(cnt, 0, (N_NODES + 512) * sizeof(int), stream);

  float* dout = (float*)d_out;

  k_hist<<<(N_EDGES + 255) / 256, 256, 0, stream>>>(ei, cnt);
  k_scan<<<1, 1024, 0, stream>>>(cnt, offs, cursor);
  k_scatter<<<(N_EDGES + 255) / 256, 256, 0, stream>>>(
      x, ei, ea, Wl2, bl2, Wr2, br2, We2, att2, cursor, rec);
  k_gather<<<(N_NODES + 255) / 256, 256, 0, stream>>>(rec, offs, nodeF);
  k_node_h<<<(N_PAD * 128) / 256, 256, 0, stream>>>(
      nodeF, Wl2, bl2, bias2, h_hi, h_lo);
  k_fc<<<512, 128, 0, stream>>>(message, Wfc, bfc, me_hi, me_lo);
  k_mfma<0><<<N_PAD / 64, 256, 0, stream>>>(h_hi, h_lo, me_hi, me_lo, colsum, dout);
  k_mfma<1><<<N_PAD / 64, 256, 0, stream>>>(h_hi, h_lo, me_hi, me_lo, colsum, dout);
}

// Round 4
// 297.390 us; speedup vs baseline: 2.0572x; 1.3434x over previous
//
#include <hip/hip_runtime.h>
#include <hip/hip_bf16.h>

#define N_NODES 50000
#define N_PAD   50048          // 782 * 64
#define N_EDGES 800000
#define NB_SCAN 196            // ceil(50000/256)

typedef __attribute__((ext_vector_type(8))) short short8;
typedef __attribute__((ext_vector_type(4))) float f32x4;

// ---------- pass 0: zero cnt + colsum (replaces slow in-graph memset) ----------
__global__ __launch_bounds__(256) void k_zero(int* __restrict__ buf)
{
  int i = blockIdx.x * 256 + threadIdx.x;
  if (i < N_NODES + 512) buf[i] = 0;
}

// ---------- pass 1: histogram of dst ----------
__global__ __launch_bounds__(256) void k_hist(
    const int* __restrict__ ei, int* __restrict__ cnt)
{
  int e = blockIdx.x * 256 + threadIdx.x;
  if (e >= N_EDGES) return;
  atomicAdd(&cnt[ei[N_EDGES + e]], 1);
}

// ---------- pass 2a: per-block exclusive scan ----------
__global__ __launch_bounds__(256) void k_scan1(
    const int* __restrict__ cnt, int* __restrict__ offs, int* __restrict__ bsum)
{
  __shared__ int sh[256];
  int b = blockIdx.x, t = threadIdx.x;
  int i = b * 256 + t;
  int v = (i < N_NODES) ? cnt[i] : 0;
  sh[t] = v;
  __syncthreads();
  #pragma unroll
  for (int off = 1; off < 256; off <<= 1) {
    int u = (t >= off) ? sh[t - off] : 0;
    __syncthreads();
    sh[t] += u;
    __syncthreads();
  }
  if (i < N_NODES) offs[i] = sh[t] - v;       // exclusive within block
  if (t == 255) bsum[b] = sh[255];
}

// ---------- pass 2b: scan of block sums (single block) ----------
__global__ __launch_bounds__(256) void k_scan2(int* __restrict__ bsum)
{
  __shared__ int sh[256];
  int t = threadIdx.x;
  int v = (t < NB_SCAN) ? bsum[t] : 0;
  sh[t] = v;
  __syncthreads();
  #pragma unroll
  for (int off = 1; off < 256; off <<= 1) {
    int u = (t >= off) ? sh[t - off] : 0;
    __syncthreads();
    sh[t] += u;
    __syncthreads();
  }
  if (t < NB_SCAN) bsum[t] = sh[t] - v;       // exclusive block offsets
}

// ---------- pass 2c: add block offsets; init cursor ----------
__global__ __launch_bounds__(256) void k_scan3(
    int* __restrict__ offs, const int* __restrict__ bsum, int* __restrict__ cursor)
{
  int b = blockIdx.x, t = threadIdx.x;
  int i = b * 256 + t;
  if (i < N_NODES) {
    int o = offs[i] + bsum[b];
    offs[i] = o;
    cursor[i] = o;
  }
  if (b == 0 && t == 0) offs[N_NODES] = N_EDGES;
}

// ---------- pass 3: fused score + scatter by dst ----------
__global__ __launch_bounds__(256) void k_scatter(
    const float* __restrict__ x, const int* __restrict__ ei,
    const float* __restrict__ ea,
    const float* __restrict__ Wl, const float* __restrict__ bl,
    const float* __restrict__ Wr, const float* __restrict__ br,
    const float* __restrict__ We, const float* __restrict__ att,
    int* __restrict__ cursor, float4* __restrict__ rec)
{
  int e = blockIdx.x * 256 + threadIdx.x;
  if (e >= N_EDGES) return;
  int s = ei[e], d = ei[N_EDGES + e];
  float x0s = x[2*s], x1s = x[2*s+1];
  float x0d = x[2*d], x1d = x[2*d+1];
  float av = ea[e];

  float s0 = 0.f, s1 = 0.f;
  #pragma unroll 8
  for (int k = 0; k < 64; ++k) {
    float m = bl[k] + br[k];
    m = fmaf(x0s, Wl[k], m);
    m = fmaf(x1s, Wl[128+k], m);
    m = fmaf(x0d, Wr[k], m);
    m = fmaf(x1d, Wr[128+k], m);
    m = fmaf(av, We[k], m);
    float l = m > 0.f ? m : 0.2f * m;
    s0 = fmaf(l, att[k], s0);
  }
  #pragma unroll 8
  for (int k = 64; k < 128; ++k) {
    float m = bl[k] + br[k];
    m = fmaf(x0s, Wl[k], m);
    m = fmaf(x1s, Wl[128+k], m);
    m = fmaf(x0d, Wr[k], m);
    m = fmaf(x1d, Wr[128+k], m);
    m = fmaf(av, We[k], m);
    float l = m > 0.f ? m : 0.2f * m;
    s1 = fmaf(l, att[k], s1);
  }
  int pos = atomicAdd(&cursor[d], 1);
  rec[pos] = make_float4(s0, s1, x0s, x1s);
}

// ---------- pass 4: per-node gather reduction (no atomics, no max pass) ----------
// Softmax shift-invariance: skip segment-max (|score| is analytically small).
__global__ __launch_bounds__(256) void k_gather(
    const float4* __restrict__ rec, const int* __restrict__ offs,
    float* __restrict__ nodeF)
{
  int n = blockIdx.x * 256 + threadIdx.x;
  if (n >= N_NODES) return;
  int a = offs[n], b = offs[n + 1];
  float D0 = 0.f, A00 = 0.f, A10 = 0.f;
  float D1 = 0.f, A01 = 0.f, A11 = 0.f;
  for (int i = a; i < b; ++i) {
    float4 r = rec[i];
    float e0 = __expf(r.x);
    float e1 = __expf(r.y);
    D0 += e0; A00 += e0 * r.z; A10 += e0 * r.w;
    D1 += e1; A01 += e1 * r.z; A11 += e1 * r.w;
  }
  float* nf = nodeF + (size_t)n * 8;
  nf[0] = D0; nf[1] = A00; nf[2] = A10;
  nf[3] = D1; nf[4] = A01; nf[5] = A11;
}

// ---------- pass 5: per-node h (factored) -> bf16 hi/lo ----------
__global__ __launch_bounds__(256) void k_node_h(
    const float* __restrict__ nodeF,
    const float* __restrict__ Wl, const float* __restrict__ bl,
    const float* __restrict__ bias,
    __hip_bfloat16* __restrict__ h_hi, __hip_bfloat16* __restrict__ h_lo)
{
  int idx = blockIdx.x * 256 + threadIdx.x;
  if (idx >= N_PAD * 128) return;
  int n = idx >> 7, k = idx & 127;
  float v = 0.f;
  if (n < N_NODES) {
    int hh = k >> 6;
    const float* nf = nodeF + (size_t)n * 8 + hh * 3;
    float D = nf[0], A0 = nf[1], A1 = nf[2];
    float r = 1.0f / (D + 1e-16f);
    v = A0*r*Wl[k] + A1*r*Wl[128+k] + D*r*bl[k] + bias[k];
    v = v > 0.f ? v : 0.f;
  }
  __hip_bfloat16 hi = __float2bfloat16(v);
  float rem = v - __bfloat162float(hi);
  h_hi[idx] = hi;
  h_lo[idx] = __float2bfloat16(rem);
}

// ---------- pass 6: msg_emb -> bf16 hi/lo ----------
__global__ __launch_bounds__(128) void k_fc(
    const float* __restrict__ msg, const float* __restrict__ Wfc,
    const float* __restrict__ bfc,
    __hip_bfloat16* __restrict__ me_hi, __hip_bfloat16* __restrict__ me_lo)
{
  int j = blockIdx.x, k = threadIdx.x;
  __shared__ float mrow[128];
  mrow[k] = msg[j*128 + k];
  __syncthreads();
  float acc = bfc[k];
  #pragma unroll 8
  for (int t = 0; t < 128; ++t) acc = fmaf(mrow[t], Wfc[t*128 + k], acc);
  __hip_bfloat16 hi = __float2bfloat16(acc);
  me_hi[j*128 + k] = hi;
  me_lo[j*128 + k] = __float2bfloat16(acc - __bfloat162float(hi));
}

// ---------- pass 7/8: split-bf16 MFMA GEMM ----------
template<int WRITE>
__global__ __launch_bounds__(256) void k_mfma(
    const __hip_bfloat16* __restrict__ h_hi, const __hip_bfloat16* __restrict__ h_lo,
    const __hip_bfloat16* __restrict__ me_hi, const __hip_bfloat16* __restrict__ me_lo,
    float* __restrict__ colsum, float* __restrict__ dout)
{
  __shared__ short8 Bt[2048];   // 32 KB: [0..1023]=hi, [1024..2047]=lo
  int tid = threadIdx.x;
  int lane = tid & 63, w = tid >> 6;
  int g = lane >> 4, c = lane & 15;
  int m0 = blockIdx.x * 64;

  // A fragments: a[rt][ks] covers row m0+rt*16+c, k = ks*32 + g*8 .. +8
  short8 a_hi[4][4], a_lo[4][4];
  #pragma unroll
  for (int rt = 0; rt < 4; ++rt) {
    size_t rowb = (size_t)(m0 + rt*16 + c) * 128 + g*8;
    #pragma unroll
    for (int ks = 0; ks < 4; ++ks) {
      a_hi[rt][ks] = *(const short8*)(h_hi + rowb + ks*32);
      a_lo[rt][ks] = *(const short8*)(h_lo + rowb + ks*32);
    }
  }

  short8 sreg[8];
  #pragma unroll
  for (int q = 0; q < 8; ++q) {
    int slot = q * 256 + tid;
    int s = slot & 1023;
    int col = s & 63, kg = s >> 6;
    const __hip_bfloat16* src = (slot < 1024) ? me_hi : me_lo;
    sreg[q] = *(const short8*)(src + (size_t)col * 128 + kg*8);
  }

  for (int cb = 0; cb < 8; ++cb) {
    #pragma unroll
    for (int q = 0; q < 8; ++q) Bt[q * 256 + tid] = sreg[q];
    if (cb + 1 < 8) {
      #pragma unroll
      for (int q = 0; q < 8; ++q) {
        int slot = q * 256 + tid;
        int s = slot & 1023;
        int col = s & 63, kg = s >> 6;
        const __hip_bfloat16* src = (slot < 1024) ? me_hi : me_lo;
        sreg[q] = *(const short8*)(src + (size_t)((cb + 1) * 64 + col) * 128 + kg*8);
      }
    }
    __syncthreads();

    f32x4 acc[4] = {f32x4{0,0,0,0}, f32x4{0,0,0,0}, f32x4{0,0,0,0}, f32x4{0,0,0,0}};
    #pragma unroll
    for (int ks = 0; ks < 4; ++ks) {
      short8 bh = Bt[(ks*4 + g) * 64 + w*16 + c];
      short8 bl = Bt[1024 + (ks*4 + g) * 64 + w*16 + c];
      #pragma unroll
      for (int rt = 0; rt < 4; ++rt) {
        acc[rt] = __builtin_amdgcn_mfma_f32_16x16x32_bf16(a_hi[rt][ks], bh, acc[rt], 0, 0, 0);
        acc[rt] = __builtin_amdgcn_mfma_f32_16x16x32_bf16(a_lo[rt][ks], bh, acc[rt], 0, 0, 0);
        acc[rt] = __builtin_amdgcn_mfma_f32_16x16x32_bf16(a_hi[rt][ks], bl, acc[rt], 0, 0, 0);
      }
    }
    __syncthreads();

    int col = cb * 64 + w * 16 + c;
    if (WRITE == 0) {
      float csum = 0.f;
      #pragma unroll
      for (int rt = 0; rt < 4; ++rt) {
        #pragma unroll
        for (int r = 0; r < 4; ++r) {
          int row = m0 + rt*16 + g*4 + r;
          csum += (row < N_NODES) ? __expf(acc[rt][r]) : 0.f;
        }
      }
      csum += __shfl_xor(csum, 16);
      csum += __shfl_xor(csum, 32);
      if (lane < 16) atomicAdd(&colsum[cb * 64 + w * 16 + lane], csum);
    } else {
      float S = colsum[col];
      float rS = 1.0f / S;
      #pragma unroll
      for (int rt = 0; rt < 4; ++rt) {
        #pragma unroll
        for (int r = 0; r < 4; ++r) {
          int row = m0 + rt*16 + g*4 + r;
          if (row < N_NODES) {
            float o = __expf(acc[rt][r]) * rS;
            dout[(size_t)row * 1024 + col] = o;
            dout[(size_t)row * 1024 + 512 + col] = o;
          }
        }
      }
    }
  }
}

extern "C" void kernel_launch(void* const* d_in, const int* in_sizes, int n_in,
                              void* d_out, int out_size, void* d_ws, size_t ws_size,
                              hipStream_t stream)
{
  const float* message = (const float*)d_in[0];
  const float* x       = (const float*)d_in[1];
  const int*   ei      = (const int*)d_in[2];
  const float* ea      = (const float*)d_in[3];
  // conv1 params (d_in[4..10]) are dead code in the reference
  const float* Wl2   = (const float*)d_in[11];
  const float* bl2   = (const float*)d_in[12];
  const float* Wr2   = (const float*)d_in[13];
  const float* br2   = (const float*)d_in[14];
  const float* We2   = (const float*)d_in[15];
  const float* att2  = (const float*)d_in[16];
  const float* bias2 = (const float*)d_in[17];
  const float* Wfc   = (const float*)d_in[18];
  const float* bfc   = (const float*)d_in[19];

  char* p = (char*)d_ws;
  float4* rec = (float4*)p;                 p += (size_t)N_EDGES * 16;
  float* nodeF = (float*)p;                 p += (size_t)N_NODES * 8 * 4;
  __hip_bfloat16* h_hi = (__hip_bfloat16*)p; p += (size_t)N_PAD * 128 * 2;
  __hip_bfloat16* h_lo = (__hip_bfloat16*)p; p += (size_t)N_PAD * 128 * 2;
  __hip_bfloat16* me_hi = (__hip_bfloat16*)p; p += 512 * 128 * 2;
  __hip_bfloat16* me_lo = (__hip_bfloat16*)p; p += 512 * 128 * 2;
  int* cnt = (int*)p;                       p += (size_t)N_NODES * 4;   // cnt+colsum adjacent
  float* colsum = (float*)p;                p += 512 * 4;
  int* offs = (int*)p;                      p += (size_t)(N_NODES + 1) * 4;
  int* cursor = (int*)p;                    p += (size_t)N_NODES * 4;
  int* bsum = (int*)p;

  float* dout = (float*)d_out;

  k_zero<<<(N_NODES + 512 + 255) / 256, 256, 0, stream>>>(cnt);
  k_hist<<<(N_EDGES + 255) / 256, 256, 0, stream>>>(ei, cnt);
  k_scan1<<<NB_SCAN, 256, 0, stream>>>(cnt, offs, bsum);
  k_scan2<<<1, 256, 0, stream>>>(bsum);
  k_scan3<<<NB_SCAN, 256, 0, stream>>>(offs, bsum, cursor);
  k_scatter<<<(N_EDGES + 255) / 256, 256, 0, stream>>>(
      x, ei, ea, Wl2, bl2, Wr2, br2, We2, att2, cursor, rec);
  k_gather<<<(N_NODES + 255) / 256, 256, 0, stream>>>(rec, offs, nodeF);
  k_node_h<<<(N_PAD * 128) / 256, 256, 0, stream>>>(
      nodeF, Wl2, bl2, bias2, h_hi, h_lo);
  k_fc<<<512, 128, 0, stream>>>(message, Wfc, bfc, me_hi, me_lo);
  k_mfma<0><<<N_PAD / 64, 256, 0, stream>>>(h_hi, h_lo, me_hi, me_lo, colsum, dout);
  k_mfma<1><<<N_PAD / 64, 256, 0, stream>>>(h_hi, h_lo, me_hi, me_lo, colsum, dout);
}

// Round 5
// 255.568 us; speedup vs baseline: 2.3939x; 1.1636x over previous
//
#include <hip/hip_runtime.h>
#include <hip/hip_bf16.h>

#define N_NODES 50000
#define N_PAD   50048          // 782 * 64
#define N_EDGES 800000
#define NB_SCAN 196            // ceil(50000/256)

typedef __attribute__((ext_vector_type(8))) short short8;
typedef __attribute__((ext_vector_type(4))) float f32x4;
typedef __attribute__((ext_vector_type(16))) float f32x16;

// ---------- pass 0: zero cnt + colsum ----------
__global__ __launch_bounds__(256) void k_zero(int* __restrict__ buf)
{
  int i = blockIdx.x * 256 + threadIdx.x;
  if (i < N_NODES + 512) buf[i] = 0;
}

// ---------- pass 1: histogram of dst ----------
__global__ __launch_bounds__(256) void k_hist(
    const int* __restrict__ ei, int* __restrict__ cnt)
{
  int e = blockIdx.x * 256 + threadIdx.x;
  if (e >= N_EDGES) return;
  atomicAdd(&cnt[ei[N_EDGES + e]], 1);
}

// ---------- pass 2a: per-block exclusive scan ----------
__global__ __launch_bounds__(256) void k_scan1(
    const int* __restrict__ cnt, int* __restrict__ offs, int* __restrict__ bsum)
{
  __shared__ int sh[256];
  int b = blockIdx.x, t = threadIdx.x;
  int i = b * 256 + t;
  int v = (i < N_NODES) ? cnt[i] : 0;
  sh[t] = v;
  __syncthreads();
  #pragma unroll
  for (int off = 1; off < 256; off <<= 1) {
    int u = (t >= off) ? sh[t - off] : 0;
    __syncthreads();
    sh[t] += u;
    __syncthreads();
  }
  if (i < N_NODES) offs[i] = sh[t] - v;
  if (t == 255) bsum[b] = sh[255];
}

// ---------- pass 2b: scan of block sums ----------
__global__ __launch_bounds__(256) void k_scan2(int* __restrict__ bsum)
{
  __shared__ int sh[256];
  int t = threadIdx.x;
  int v = (t < NB_SCAN) ? bsum[t] : 0;
  sh[t] = v;
  __syncthreads();
  #pragma unroll
  for (int off = 1; off < 256; off <<= 1) {
    int u = (t >= off) ? sh[t - off] : 0;
    __syncthreads();
    sh[t] += u;
    __syncthreads();
  }
  if (t < NB_SCAN) bsum[t] = sh[t] - v;
}

// ---------- pass 2c: add block offsets; init cursor ----------
__global__ __launch_bounds__(256) void k_scan3(
    int* __restrict__ offs, const int* __restrict__ bsum, int* __restrict__ cursor)
{
  int b = blockIdx.x, t = threadIdx.x;
  int i = b * 256 + t;
  if (i < N_NODES) {
    int o = offs[i] + bsum[b];
    offs[i] = o;
    cursor[i] = o;
  }
  if (b == 0 && t == 0) offs[N_NODES] = N_EDGES;
}

// ---------- pass 3: fused score + scatter by dst ----------
__global__ __launch_bounds__(256) void k_scatter(
    const float* __restrict__ x, const int* __restrict__ ei,
    const float* __restrict__ ea,
    const float* __restrict__ Wl, const float* __restrict__ bl,
    const float* __restrict__ Wr, const float* __restrict__ br,
    const float* __restrict__ We, const float* __restrict__ att,
    int* __restrict__ cursor, float4* __restrict__ rec)
{
  int e = blockIdx.x * 256 + threadIdx.x;
  if (e >= N_EDGES) return;
  int s = ei[e], d = ei[N_EDGES + e];
  float x0s = x[2*s], x1s = x[2*s+1];
  float x0d = x[2*d], x1d = x[2*d+1];
  float av = ea[e];

  float s0 = 0.f, s1 = 0.f;
  #pragma unroll 8
  for (int k = 0; k < 64; ++k) {
    float m = bl[k] + br[k];
    m = fmaf(x0s, Wl[k], m);
    m = fmaf(x1s, Wl[128+k], m);
    m = fmaf(x0d, Wr[k], m);
    m = fmaf(x1d, Wr[128+k], m);
    m = fmaf(av, We[k], m);
    float l = m > 0.f ? m : 0.2f * m;
    s0 = fmaf(l, att[k], s0);
  }
  #pragma unroll 8
  for (int k = 64; k < 128; ++k) {
    float m = bl[k] + br[k];
    m = fmaf(x0s, Wl[k], m);
    m = fmaf(x1s, Wl[128+k], m);
    m = fmaf(x0d, Wr[k], m);
    m = fmaf(x1d, Wr[128+k], m);
    m = fmaf(av, We[k], m);
    float l = m > 0.f ? m : 0.2f * m;
    s1 = fmaf(l, att[k], s1);
  }
  int pos = atomicAdd(&cursor[d], 1);
  rec[pos] = make_float4(s0, s1, x0s, x1s);
}

// ---------- pass 4: per-node gather reduction ----------
__global__ __launch_bounds__(256) void k_gather(
    const float4* __restrict__ rec, const int* __restrict__ offs,
    float* __restrict__ nodeF)
{
  int n = blockIdx.x * 256 + threadIdx.x;
  if (n >= N_NODES) return;
  int a = offs[n], b = offs[n + 1];
  float D0 = 0.f, A00 = 0.f, A10 = 0.f;
  float D1 = 0.f, A01 = 0.f, A11 = 0.f;
  for (int i = a; i < b; ++i) {
    float4 r = rec[i];
    float e0 = __expf(r.x);
    float e1 = __expf(r.y);
    D0 += e0; A00 += e0 * r.z; A10 += e0 * r.w;
    D1 += e1; A01 += e1 * r.z; A11 += e1 * r.w;
  }
  float* nf = nodeF + (size_t)n * 8;
  nf[0] = D0; nf[1] = A00; nf[2] = A10;
  nf[3] = D1; nf[4] = A01; nf[5] = A11;
}

// ---------- pass 5: msg_emb -> bf16 hi/lo ----------
__global__ __launch_bounds__(128) void k_fc(
    const float* __restrict__ msg, const float* __restrict__ Wfc,
    const float* __restrict__ bfc,
    __hip_bfloat16* __restrict__ me_hi, __hip_bfloat16* __restrict__ me_lo)
{
  int j = blockIdx.x, k = threadIdx.x;
  __shared__ float mrow[128];
  mrow[k] = msg[j*128 + k];
  __syncthreads();
  float acc = bfc[k];
  #pragma unroll 8
  for (int t = 0; t < 128; ++t) acc = fmaf(mrow[t], Wfc[t*128 + k], acc);
  __hip_bfloat16 hi = __float2bfloat16(acc);
  me_hi[j*128 + k] = hi;
  me_lo[j*128 + k] = __float2bfloat16(acc - __bfloat162float(hi));
}

// ---------- pass 6/7: 32x32x16 split-bf16 MFMA GEMM, h fused from nodeF ----------
// Block: 256 thr = 4 waves, tile 64 rows; loop 8 col-blocks of 64.
// Wave w: rt=w>>1 (row half), ct=w&1 (col half) -> 32x32 output tile per cb.
// A-frags in regs (computed from nodeF); B staged global->LDS, XOR-swizzled
// (slot = col*16 + (ku ^ (col&7))) -> conflict-free ds_read_b128.
// PASS 0: accumulate colsum (LDS colacc, one flush). PASS 1: normalize+store.
template<int PASS>
__global__ __launch_bounds__(256, 3) void k_mfma(
    const float* __restrict__ nodeF,
    const float* __restrict__ Wl, const float* __restrict__ bl,
    const float* __restrict__ bias,
    const __hip_bfloat16* __restrict__ me_hi, const __hip_bfloat16* __restrict__ me_lo,
    float* __restrict__ colsum, float* __restrict__ dout)
{
  __shared__ short8 Bt[2048];          // 32KB: [0..1023]=hi, [1024..2047]=lo
  __shared__ float colacc[2][512];     // only used when PASS==0

  int tid = threadIdx.x;
  int l = tid & 63, w = tid >> 6;
  int rt = w >> 1, ct = w & 1;
  int lrow = l & 31, lhalf = l >> 5;
  int m0 = blockIdx.x * 64;
  int row = m0 + rt * 32 + lrow;

  if (PASS == 0) {
    #pragma unroll
    for (int q = 0; q < 4; ++q) ((float*)colacc)[q * 256 + tid] = 0.f;
  }

  // ---- A fragments from nodeF (h computed on the fly, split hi/lo) ----
  float c0a = 0.f, c0b = 0.f, c0d = 0.f, c1a = 0.f, c1b = 0.f, c1d = 0.f;
  bool live = row < N_NODES;
  if (live) {
    const float* nf = nodeF + (size_t)row * 8;
    float D0 = nf[0], A00 = nf[1], A10 = nf[2];
    float D1 = nf[3], A01 = nf[4], A11 = nf[5];
    float r0 = 1.0f / (D0 + 1e-16f), r1 = 1.0f / (D1 + 1e-16f);
    c0a = A00 * r0; c0b = A10 * r0; c0d = D0 * r0;
    c1a = A01 * r1; c1b = A11 * r1; c1d = D1 * r1;
  }
  short8 a_hi[8], a_lo[8];
  #pragma unroll
  for (int ks = 0; ks < 8; ++ks) {
    int k0 = ks * 16 + lhalf * 8;
    float ca = (ks < 4) ? c0a : c1a;
    float cbv = (ks < 4) ? c0b : c1b;
    float cd = (ks < 4) ? c0d : c1d;
    float wA[8], wB[8], wC[8], wD[8];
    *(float4*)&wA[0] = *(const float4*)(Wl + k0);
    *(float4*)&wA[4] = *(const float4*)(Wl + k0 + 4);
    *(float4*)&wB[0] = *(const float4*)(Wl + 128 + k0);
    *(float4*)&wB[4] = *(const float4*)(Wl + 128 + k0 + 4);
    *(float4*)&wC[0] = *(const float4*)(bl + k0);
    *(float4*)&wC[4] = *(const float4*)(bl + k0 + 4);
    *(float4*)&wD[0] = *(const float4*)(bias + k0);
    *(float4*)&wD[4] = *(const float4*)(bias + k0 + 4);
    short8 hi8, lo8;
    #pragma unroll
    for (int j = 0; j < 8; ++j) {
      float v = ca * wA[j] + cbv * wB[j] + cd * wC[j] + wD[j];
      v = (live && v > 0.f) ? v : 0.f;
      __hip_bfloat16 hb = __float2bfloat16(v);
      float rem = v - __bfloat162float(hb);
      __hip_bfloat16 lb = __float2bfloat16(rem);
      short hs, ls;
      __builtin_memcpy(&hs, &hb, 2);
      __builtin_memcpy(&ls, &lb, 2);
      hi8[j] = hs;
      lo8[j] = ls;
    }
    a_hi[ks] = hi8;
    a_lo[ks] = lo8;
  }

  for (int cb = 0; cb < 8; ++cb) {
    __syncthreads();   // previous cb's Bt reads done
    // stage B tile (64 cols x 128 k, hi+lo), coalesced, XOR-swizzled
    #pragma unroll
    for (int q = 0; q < 4; ++q) {
      int lin = q * 256 + tid;            // 0..1023 16B-chunks
      int col = lin >> 4, ku = lin & 15;
      int slot = col * 16 + (ku ^ (col & 7));
      size_t gb = ((size_t)(cb * 64 + col) << 7) + ku * 8;
      Bt[slot] = *(const short8*)(me_hi + gb);
      Bt[1024 + slot] = *(const short8*)(me_lo + gb);
    }
    __syncthreads();

    f32x16 acc = {0.f};
    #pragma unroll
    for (int ks = 0; ks < 8; ++ks) {
      int ku = ks * 2 + lhalf;
      int colB = ct * 32 + lrow;
      int slot = colB * 16 + (ku ^ (colB & 7));
      short8 bh = Bt[slot];
      short8 blo = Bt[1024 + slot];
      acc = __builtin_amdgcn_mfma_f32_32x32x16_bf16(a_hi[ks], bh, acc, 0, 0, 0);
      acc = __builtin_amdgcn_mfma_f32_32x32x16_bf16(a_lo[ks], bh, acc, 0, 0, 0);
      acc = __builtin_amdgcn_mfma_f32_32x32x16_bf16(a_hi[ks], blo, acc, 0, 0, 0);
    }

    int col = cb * 64 + ct * 32 + lrow;
    if (PASS == 0) {
      float csum = 0.f;
      #pragma unroll
      for (int i = 0; i < 16; ++i) {
        int grow = m0 + rt * 32 + (i & 3) + 8 * (i >> 2) + 4 * lhalf;
        csum += (grow < N_NODES) ? __expf(acc[i]) : 0.f;
      }
      csum += __shfl_xor(csum, 32);
      if (l < 32) colacc[rt][cb * 64 + ct * 32 + l] += csum;
    } else {
      float rS = 1.0f / colsum[col];
      #pragma unroll
      for (int i = 0; i < 16; ++i) {
        int grow = m0 + rt * 32 + (i & 3) + 8 * (i >> 2) + 4 * lhalf;
        if (grow < N_NODES) {
          float o = __expf(acc[i]) * rS;
          dout[(size_t)grow * 1024 + col] = o;
          dout[(size_t)grow * 1024 + 512 + col] = o;
        }
      }
    }
  }

  if (PASS == 0) {
    __syncthreads();
    atomicAdd(&colsum[tid], colacc[0][tid] + colacc[1][tid]);
    atomicAdd(&colsum[tid + 256], colacc[0][tid + 256] + colacc[1][tid + 256]);
  }
}

extern "C" void kernel_launch(void* const* d_in, const int* in_sizes, int n_in,
                              void* d_out, int out_size, void* d_ws, size_t ws_size,
                              hipStream_t stream)
{
  const float* message = (const float*)d_in[0];
  const float* x       = (const float*)d_in[1];
  const int*   ei      = (const int*)d_in[2];
  const float* ea      = (const float*)d_in[3];
  // conv1 params (d_in[4..10]) are dead code in the reference
  const float* Wl2   = (const float*)d_in[11];
  const float* bl2   = (const float*)d_in[12];
  const float* Wr2   = (const float*)d_in[13];
  const float* br2   = (const float*)d_in[14];
  const float* We2   = (const float*)d_in[15];
  const float* att2  = (const float*)d_in[16];
  const float* bias2 = (const float*)d_in[17];
  const float* Wfc   = (const float*)d_in[18];
  const float* bfc   = (const float*)d_in[19];

  char* p = (char*)d_ws;
  float4* rec = (float4*)p;                  p += (size_t)N_EDGES * 16;
  float* nodeF = (float*)p;                  p += (size_t)N_NODES * 8 * 4;
  __hip_bfloat16* me_hi = (__hip_bfloat16*)p; p += 512 * 128 * 2;
  __hip_bfloat16* me_lo = (__hip_bfloat16*)p; p += 512 * 128 * 2;
  int* cnt = (int*)p;                        p += (size_t)N_NODES * 4;  // cnt+colsum adjacent (zeroed together)
  float* colsum = (float*)p;                 p += 512 * 4;
  int* offs = (int*)p;                       p += (size_t)(N_NODES + 1) * 4;
  int* cursor = (int*)p;                     p += (size_t)N_NODES * 4;
  int* bsum = (int*)p;

  float* dout = (float*)d_out;

  k_zero<<<(N_NODES + 512 + 255) / 256, 256, 0, stream>>>(cnt);
  k_hist<<<(N_EDGES + 255) / 256, 256, 0, stream>>>(ei, cnt);
  k_scan1<<<NB_SCAN, 256, 0, stream>>>(cnt, offs, bsum);
  k_scan2<<<1, 256, 0, stream>>>(bsum);
  k_scan3<<<NB_SCAN, 256, 0, stream>>>(offs, bsum, cursor);
  k_scatter<<<(N_EDGES + 255) / 256, 256, 0, stream>>>(
      x, ei, ea, Wl2, bl2, Wr2, br2, We2, att2, cursor, rec);
  k_gather<<<(N_NODES + 255) / 256, 256, 0, stream>>>(rec, offs, nodeF);
  k_fc<<<512, 128, 0, stream>>>(message, Wfc, bfc, me_hi, me_lo);
  k_mfma<0><<<N_PAD / 64, 256, 0, stream>>>(
      nodeF, Wl2, bl2, bias2, me_hi, me_lo, colsum, dout);
  k_mfma<1><<<N_PAD / 64, 256, 0, stream>>>(
      nodeF, Wl2, bl2, bias2, me_hi, me_lo, colsum, dout);
}

// Round 7
// 216.050 us; speedup vs baseline: 2.8317x; 1.1829x over previous
//
#include <hip/hip_runtime.h>
#include <hip/hip_bf16.h>
#include <hip/hip_cooperative_groups.h>

namespace cg = cooperative_groups;

#define N_NODES 50000
#define N_PAD   50048          // 782 * 64
#define N_EDGES 800000
#define GRID    512
#define BLK     256
#define STRIDE  (GRID*BLK)     // 131072
#define CHUNK   98             // 512*98 = 50176 >= 50000
#define NTILES  782
#define NB_SCAN 196            // fallback path: ceil(50000/256)

typedef __attribute__((ext_vector_type(8))) short short8;
typedef __attribute__((ext_vector_type(16))) float f32x16;

struct Params {
  const float* msg; const float* x; const int* ei; const float* ea;
  const float* Wl; const float* bl; const float* Wr; const float* br;
  const float* We; const float* att; const float* bias;
  const float* Wfc; const float* bfc;
  float4* rec; float* nodeF;
  __hip_bfloat16* me_hi; __hip_bfloat16* me_lo;
  int* cnt; float* colsum; int* offs; int* cursor; int* bsum;
  float* dout;
};

// ================= shared MFMA tile body =================
// PASS 0: colsum accumulate into LDS colacc; PASS 1: normalize + coalesced
// store via LDS transpose (xp stride 68 floats = 16B aligned, 2-way banks).
template<int PASS>
__device__ __forceinline__ void mfma_tile(const Params& P, int tile, char* SMEM)
{
  short8* Bt = (short8*)SMEM;                       // 32 KB
  float* colacc = (float*)(SMEM + 32768);           // PASS0: 4 KB
  float* xp     = (float*)(SMEM + 32768);           // PASS1: 64*68*4 = 17408 B
  float* rcol   = (float*)(SMEM + 50176);           // PASS1: 2 KB

  const int tid = threadIdx.x;
  const int l = tid & 63, w = tid >> 6;
  const int rt = w >> 1, ct = w & 1;
  const int lrow = l & 31, lhalf = l >> 5;
  const int m0 = tile * 64;
  const int row = m0 + rt * 32 + lrow;

  // A fragments from nodeF (h computed on the fly, split bf16 hi/lo)
  float c0a = 0.f, c0b = 0.f, c0d = 0.f, c1a = 0.f, c1b = 0.f, c1d = 0.f;
  bool live = row < N_NODES;
  if (live) {
    const float* nf = P.nodeF + (size_t)row * 8;
    float D0 = nf[0], A00 = nf[1], A10 = nf[2];
    float D1 = nf[3], A01 = nf[4], A11 = nf[5];
    float r0 = 1.0f / (D0 + 1e-16f), r1 = 1.0f / (D1 + 1e-16f);
    c0a = A00 * r0; c0b = A10 * r0; c0d = D0 * r0;
    c1a = A01 * r1; c1b = A11 * r1; c1d = D1 * r1;
  }
  short8 a_hi[8], a_lo[8];
  #pragma unroll
  for (int ks = 0; ks < 8; ++ks) {
    int k0 = ks * 16 + lhalf * 8;
    float ca = (ks < 4) ? c0a : c1a;
    float cbv = (ks < 4) ? c0b : c1b;
    float cd = (ks < 4) ? c0d : c1d;
    float wA[8], wB[8], wC[8], wD[8];
    *(float4*)&wA[0] = *(const float4*)(P.Wl + k0);
    *(float4*)&wA[4] = *(const float4*)(P.Wl + k0 + 4);
    *(float4*)&wB[0] = *(const float4*)(P.Wl + 128 + k0);
    *(float4*)&wB[4] = *(const float4*)(P.Wl + 128 + k0 + 4);
    *(float4*)&wC[0] = *(const float4*)(P.bl + k0);
    *(float4*)&wC[4] = *(const float4*)(P.bl + k0 + 4);
    *(float4*)&wD[0] = *(const float4*)(P.bias + k0);
    *(float4*)&wD[4] = *(const float4*)(P.bias + k0 + 4);
    short8 hi8, lo8;
    #pragma unroll
    for (int j = 0; j < 8; ++j) {
      float v = ca * wA[j] + cbv * wB[j] + cd * wC[j] + wD[j];
      v = (live && v > 0.f) ? v : 0.f;
      __hip_bfloat16 hb = __float2bfloat16(v);
      float rem = v - __bfloat162float(hb);
      __hip_bfloat16 lb = __float2bfloat16(rem);
      short hs, ls;
      __builtin_memcpy(&hs, &hb, 2);
      __builtin_memcpy(&ls, &lb, 2);
      hi8[j] = hs; lo8[j] = ls;
    }
    a_hi[ks] = hi8; a_lo[ks] = lo8;
  }

  for (int cb = 0; cb < 8; ++cb) {
    __syncthreads();     // prev cb's Bt/xp reads done
    #pragma unroll
    for (int q = 0; q < 4; ++q) {
      int lin = q * 256 + tid;
      int col = lin >> 4, ku = lin & 15;
      int slot = col * 16 + (ku ^ (col & 7));
      size_t gb = ((size_t)(cb * 64 + col) << 7) + ku * 8;
      Bt[slot] = *(const short8*)(P.me_hi + gb);
      Bt[1024 + slot] = *(const short8*)(P.me_lo + gb);
    }
    __syncthreads();

    f32x16 acc = {0.f};
    #pragma unroll
    for (int ks = 0; ks < 8; ++ks) {
      int ku = ks * 2 + lhalf;
      int colB = ct * 32 + lrow;
      int slot = colB * 16 + (ku ^ (colB & 7));
      short8 bh = Bt[slot];
      short8 blo = Bt[1024 + slot];
      acc = __builtin_amdgcn_mfma_f32_32x32x16_bf16(a_hi[ks], bh, acc, 0, 0, 0);
      acc = __builtin_amdgcn_mfma_f32_32x32x16_bf16(a_lo[ks], bh, acc, 0, 0, 0);
      acc = __builtin_amdgcn_mfma_f32_32x32x16_bf16(a_hi[ks], blo, acc, 0, 0, 0);
    }

    if (PASS == 0) {
      float csum = 0.f;
      #pragma unroll
      for (int i = 0; i < 16; ++i) {
        int grow = m0 + rt * 32 + (i & 3) + 8 * (i >> 2) + 4 * lhalf;
        csum += (grow < N_NODES) ? __expf(acc[i]) : 0.f;
      }
      csum += __shfl_xor(csum, 32);
      if (l < 32) colacc[rt * 512 + cb * 64 + ct * 32 + l] += csum;
    } else {
      #pragma unroll
      for (int i = 0; i < 16; ++i) {
        int rl = rt * 32 + (i & 3) + 8 * (i >> 2) + 4 * lhalf;
        xp[rl * 68 + ct * 32 + lrow] = __expf(acc[i]);
      }
      __syncthreads();
      #pragma unroll
      for (int q = 0; q < 4; ++q) {
        int fid = q * 256 + tid;
        int rl = fid >> 4, c4 = fid & 15;
        int grow = m0 + rl;
        float4 v = *(float4*)&xp[rl * 68 + c4 * 4];
        float4 s = *(const float4*)&rcol[cb * 64 + c4 * 4];
        v.x *= s.x; v.y *= s.y; v.z *= s.z; v.w *= s.w;
        if (grow < N_NODES) {
          *(float4*)&P.dout[(size_t)grow * 1024 + cb * 64 + c4 * 4] = v;
          *(float4*)&P.dout[(size_t)grow * 1024 + 512 + cb * 64 + c4 * 4] = v;
        }
      }
    }
  }
}

// ================= cooperative mega-kernel =================
__global__ __launch_bounds__(BLK, 2) void k_all(Params P)
{
  cg::grid_group gg = cg::this_grid();
  __shared__ __align__(16) char SMEM[52224];
  const int b = blockIdx.x, t = threadIdx.x;

  // P0: fc (blocks 0-255, 2 rows each) + zero cnt/colsum (blocks 256-453)
  if (b < 256) {
    float* mrow = (float*)SMEM;
    int r = 2 * b + (t >> 7);
    int col = t & 127;
    mrow[t] = P.msg[r * 128 + col];
    __syncthreads();
    int base = (t >> 7) * 128;
    float acc = P.bfc[col];
    #pragma unroll 8
    for (int k = 0; k < 128; ++k) acc = fmaf(mrow[base + k], P.Wfc[k * 128 + col], acc);
    __hip_bfloat16 hi = __float2bfloat16(acc);
    P.me_hi[r * 128 + col] = hi;
    P.me_lo[r * 128 + col] = __float2bfloat16(acc - __bfloat162float(hi));
  } else if (b < 454) {
    int i = (b - 256) * 256 + t;
    if (i < N_NODES + 512) P.cnt[i] = 0;   // cnt + adjacent colsum
  }
  gg.sync();

  // P1: histogram of dst
  for (int e = b * BLK + t; e < N_EDGES; e += STRIDE)
    atomicAdd(&P.cnt[P.ei[N_EDGES + e]], 1);
  gg.sync();

  // P2: per-chunk local exclusive scan (CHUNK=98, scan width 128)
  {
    int* sh = (int*)SMEM;
    int base = b * CHUNK;
    if (t < 128) sh[t] = 0;
    __syncthreads();
    int v = 0;
    if (t < CHUNK && base + t < N_NODES) { v = P.cnt[base + t]; sh[t] = v; }
    __syncthreads();
    #pragma unroll
    for (int off = 1; off < 128; off <<= 1) {
      int u = (t < 128 && t >= off) ? sh[t - off] : 0;
      __syncthreads();
      if (t < 128) sh[t] += u;
      __syncthreads();
    }
    if (t < CHUNK && base + t < N_NODES) P.offs[base + t] = sh[t] - v;
    if (t == 0) P.bsum[b] = sh[127];
  }
  gg.sync();

  // P3: every block scans the 512 block-sums; add-back + cursor init
  {
    int* eb = (int*)SMEM;                // 512 exclusive values
    int* s3 = eb + 512;                  // 256 partials
    int x0 = P.bsum[2 * t], x1 = P.bsum[2 * t + 1];
    s3[t] = x0 + x1;
    __syncthreads();
    #pragma unroll
    for (int off = 1; off < 256; off <<= 1) {
      int u = (t >= off) ? s3[t - off] : 0;
      __syncthreads();
      s3[t] += u;
      __syncthreads();
    }
    int p = t ? s3[t - 1] : 0;
    eb[2 * t] = p; eb[2 * t + 1] = p + x0;
    __syncthreads();
    int pb = eb[b];
    int base = b * CHUNK;
    if (t < CHUNK && base + t < N_NODES) {
      int o = P.offs[base + t] + pb;
      P.offs[base + t] = o;
      P.cursor[base + t] = o;
    }
    if (b == 0 && t == 0) P.offs[N_NODES] = N_EDGES;
  }
  gg.sync();

  // P4: fused score + scatter
  for (int e = b * BLK + t; e < N_EDGES; e += STRIDE) {
    int s = P.ei[e], d = P.ei[N_EDGES + e];
    float x0s = P.x[2*s], x1s = P.x[2*s+1];
    float x0d = P.x[2*d], x1d = P.x[2*d+1];
    float av = P.ea[e];
    float s0 = 0.f, s1 = 0.f;
    #pragma unroll 8
    for (int k = 0; k < 64; ++k) {
      float m = P.bl[k] + P.br[k];
      m = fmaf(x0s, P.Wl[k], m);
      m = fmaf(x1s, P.Wl[128+k], m);
      m = fmaf(x0d, P.Wr[k], m);
      m = fmaf(x1d, P.Wr[128+k], m);
      m = fmaf(av, P.We[k], m);
      float lk = m > 0.f ? m : 0.2f * m;
      s0 = fmaf(lk, P.att[k], s0);
    }
    #pragma unroll 8
    for (int k = 64; k < 128; ++k) {
      float m = P.bl[k] + P.br[k];
      m = fmaf(x0s, P.Wl[k], m);
      m = fmaf(x1s, P.Wl[128+k], m);
      m = fmaf(x0d, P.Wr[k], m);
      m = fmaf(x1d, P.Wr[128+k], m);
      m = fmaf(av, P.We[k], m);
      float lk = m > 0.f ? m : 0.2f * m;
      s1 = fmaf(lk, P.att[k], s1);
    }
    int pos = atomicAdd(&P.cursor[d], 1);
    P.rec[pos] = make_float4(s0, s1, x0s, x1s);
  }
  gg.sync();

  // P5: per-node gather reduction
  {
    int n = b * BLK + t;
    if (n < N_NODES) {
      int a = P.offs[n], bb = P.offs[n + 1];
      float D0 = 0.f, A00 = 0.f, A10 = 0.f;
      float D1 = 0.f, A01 = 0.f, A11 = 0.f;
      for (int i = a; i < bb; ++i) {
        float4 r = P.rec[i];
        float e0 = __expf(r.x);
        float e1 = __expf(r.y);
        D0 += e0; A00 += e0 * r.z; A10 += e0 * r.w;
        D1 += e1; A01 += e1 * r.z; A11 += e1 * r.w;
      }
      float* nf = P.nodeF + (size_t)n * 8;
      nf[0] = D0; nf[1] = A00; nf[2] = A10;
      nf[3] = D1; nf[4] = A01; nf[5] = A11;
    }
  }
  gg.sync();

  // P6: MFMA colsum pass
  {
    float* colacc = (float*)(SMEM + 32768);
    #pragma unroll
    for (int q = 0; q < 4; ++q) colacc[q * 256 + t] = 0.f;
    __syncthreads();
    for (int tile = b; tile < NTILES; tile += GRID)
      mfma_tile<0>(P, tile, SMEM);
    __syncthreads();
    atomicAdd(&P.colsum[t], colacc[t] + colacc[512 + t]);
    atomicAdd(&P.colsum[t + 256], colacc[256 + t] + colacc[768 + t]);
  }
  gg.sync();

  // P7: MFMA normalize + store pass
  {
    float* rcol = (float*)(SMEM + 50176);
    rcol[t] = 1.0f / P.colsum[t];
    rcol[t + 256] = 1.0f / P.colsum[t + 256];
    __syncthreads();
    for (int tile = b; tile < NTILES; tile += GRID)
      mfma_tile<1>(P, tile, SMEM);
  }
}

// ================= fallback multi-kernel path (proven round-5) =============
__global__ __launch_bounds__(256) void k_zero(int* __restrict__ buf)
{
  int i = blockIdx.x * 256 + threadIdx.x;
  if (i < N_NODES + 512) buf[i] = 0;
}

__global__ __launch_bounds__(256) void k_hist(
    const int* __restrict__ ei, int* __restrict__ cnt)
{
  int e = blockIdx.x * 256 + threadIdx.x;
  if (e >= N_EDGES) return;
  atomicAdd(&cnt[ei[N_EDGES + e]], 1);
}

__global__ __launch_bounds__(256) void k_scan1(
    const int* __restrict__ cnt, int* __restrict__ offs, int* __restrict__ bsum)
{
  __shared__ int sh[256];
  int b = blockIdx.x, t = threadIdx.x;
  int i = b * 256 + t;
  int v = (i < N_NODES) ? cnt[i] : 0;
  sh[t] = v;
  __syncthreads();
  #pragma unroll
  for (int off = 1; off < 256; off <<= 1) {
    int u = (t >= off) ? sh[t - off] : 0;
    __syncthreads();
    sh[t] += u;
    __syncthreads();
  }
  if (i < N_NODES) offs[i] = sh[t] - v;
  if (t == 255) bsum[b] = sh[255];
}

__global__ __launch_bounds__(256) void k_scan2(int* __restrict__ bsum)
{
  __shared__ int sh[256];
  int t = threadIdx.x;
  int v = (t < NB_SCAN) ? bsum[t] : 0;
  sh[t] = v;
  __syncthreads();
  #pragma unroll
  for (int off = 1; off < 256; off <<= 1) {
    int u = (t >= off) ? sh[t - off] : 0;
    __syncthreads();
    sh[t] += u;
    __syncthreads();
  }
  if (t < NB_SCAN) bsum[t] = sh[t] - v;
}

__global__ __launch_bounds__(256) void k_scan3(
    int* __restrict__ offs, const int* __restrict__ bsum, int* __restrict__ cursor)
{
  int b = blockIdx.x, t = threadIdx.x;
  int i = b * 256 + t;
  if (i < N_NODES) {
    int o = offs[i] + bsum[b];
    offs[i] = o;
    cursor[i] = o;
  }
  if (b == 0 && t == 0) offs[N_NODES] = N_EDGES;
}

__global__ __launch_bounds__(256) void k_scatter(Params P)
{
  int e = blockIdx.x * 256 + threadIdx.x;
  if (e >= N_EDGES) return;
  int s = P.ei[e], d = P.ei[N_EDGES + e];
  float x0s = P.x[2*s], x1s = P.x[2*s+1];
  float x0d = P.x[2*d], x1d = P.x[2*d+1];
  float av = P.ea[e];
  float s0 = 0.f, s1 = 0.f;
  #pragma unroll 8
  for (int k = 0; k < 64; ++k) {
    float m = P.bl[k] + P.br[k];
    m = fmaf(x0s, P.Wl[k], m);
    m = fmaf(x1s, P.Wl[128+k], m);
    m = fmaf(x0d, P.Wr[k], m);
    m = fmaf(x1d, P.Wr[128+k], m);
    m = fmaf(av, P.We[k], m);
    float lk = m > 0.f ? m : 0.2f * m;
    s0 = fmaf(lk, P.att[k], s0);
  }
  #pragma unroll 8
  for (int k = 64; k < 128; ++k) {
    float m = P.bl[k] + P.br[k];
    m = fmaf(x0s, P.Wl[k], m);
    m = fmaf(x1s, P.Wl[128+k], m);
    m = fmaf(x0d, P.Wr[k], m);
    m = fmaf(x1d, P.Wr[128+k], m);
    m = fmaf(av, P.We[k], m);
    float lk = m > 0.f ? m : 0.2f * m;
    s1 = fmaf(lk, P.att[k], s1);
  }
  int pos = atomicAdd(&P.cursor[d], 1);
  P.rec[pos] = make_float4(s0, s1, x0s, x1s);
}

__global__ __launch_bounds__(256) void k_gather(Params P)
{
  int n = blockIdx.x * 256 + threadIdx.x;
  if (n >= N_NODES) return;
  int a = P.offs[n], b = P.offs[n + 1];
  float D0 = 0.f, A00 = 0.f, A10 = 0.f;
  float D1 = 0.f, A01 = 0.f, A11 = 0.f;
  for (int i = a; i < b; ++i) {
    float4 r = P.rec[i];
    float e0 = __expf(r.x);
    float e1 = __expf(r.y);
    D0 += e0; A00 += e0 * r.z; A10 += e0 * r.w;
    D1 += e1; A01 += e1 * r.z; A11 += e1 * r.w;
  }
  float* nf = P.nodeF + (size_t)n * 8;
  nf[0] = D0; nf[1] = A00; nf[2] = A10;
  nf[3] = D1; nf[4] = A01; nf[5] = A11;
}

__global__ __launch_bounds__(128) void k_fc(Params P)
{
  int j = blockIdx.x, k = threadIdx.x;
  __shared__ float mrow[128];
  mrow[k] = P.msg[j*128 + k];
  __syncthreads();
  float acc = P.bfc[k];
  #pragma unroll 8
  for (int t = 0; t < 128; ++t) acc = fmaf(mrow[t], P.Wfc[t*128 + k], acc);
  __hip_bfloat16 hi = __float2bfloat16(acc);
  P.me_hi[j*128 + k] = hi;
  P.me_lo[j*128 + k] = __float2bfloat16(acc - __bfloat162float(hi));
}

template<int PASS>
__global__ __launch_bounds__(256, 2) void k_mfma(Params P)
{
  __shared__ __align__(16) char SMEM[52224];
  int tid = threadIdx.x;
  if (PASS == 0) {
    float* colacc = (float*)(SMEM + 32768);
    #pragma unroll
    for (int q = 0; q < 4; ++q) colacc[q * 256 + tid] = 0.f;
    __syncthreads();
    mfma_tile<0>(P, blockIdx.x, SMEM);
    __syncthreads();
    atomicAdd(&P.colsum[tid], colacc[tid] + colacc[512 + tid]);
    atomicAdd(&P.colsum[tid + 256], colacc[256 + tid] + colacc[768 + tid]);
  } else {
    float* rcol = (float*)(SMEM + 50176);
    rcol[tid] = 1.0f / P.colsum[tid];
    rcol[tid + 256] = 1.0f / P.colsum[tid + 256];
    __syncthreads();
    mfma_tile<1>(P, blockIdx.x, SMEM);
  }
}

extern "C" void kernel_launch(void* const* d_in, const int* in_sizes, int n_in,
                              void* d_out, int out_size, void* d_ws, size_t ws_size,
                              hipStream_t stream)
{
  Params P;
  P.msg = (const float*)d_in[0];
  P.x   = (const float*)d_in[1];
  P.ei  = (const int*)d_in[2];
  P.ea  = (const float*)d_in[3];
  // conv1 params (d_in[4..10]) are dead code in the reference
  P.Wl   = (const float*)d_in[11];
  P.bl   = (const float*)d_in[12];
  P.Wr   = (const float*)d_in[13];
  P.br   = (const float*)d_in[14];
  P.We   = (const float*)d_in[15];
  P.att  = (const float*)d_in[16];
  P.bias = (const float*)d_in[17];
  P.Wfc  = (const float*)d_in[18];
  P.bfc  = (const float*)d_in[19];

  char* p = (char*)d_ws;
  P.rec = (float4*)p;                    p += (size_t)N_EDGES * 16;
  P.nodeF = (float*)p;                   p += (size_t)N_NODES * 8 * 4;
  P.me_hi = (__hip_bfloat16*)p;          p += 512 * 128 * 2;
  P.me_lo = (__hip_bfloat16*)p;          p += 512 * 128 * 2;
  P.cnt = (int*)p;                       p += (size_t)N_NODES * 4;   // colsum adjacent
  P.colsum = (float*)p;                  p += 512 * 4;
  P.offs = (int*)p;                      p += (size_t)(N_NODES + 1) * 4;
  P.cursor = (int*)p;                    p += (size_t)N_NODES * 4;
  P.bsum = (int*)p;                      p += GRID * 4;
  P.dout = (float*)d_out;

  // occupancy-gated cooperative launch, multi-kernel fallback
  int maxBlk = 0;
  hipError_t qerr = hipOccupancyMaxActiveBlocksPerMultiprocessor(&maxBlk, k_all, BLK, 0);
  if (qerr == hipSuccess && maxBlk >= 2) {
    void* args[] = { &P };
    hipError_t lerr = hipLaunchCooperativeKernel((void*)k_all, dim3(GRID), dim3(BLK),
                                                 args, 0, stream);
    if (lerr == hipSuccess) return;
  }

  // ---- fallback: proven multi-kernel pipeline ----
  k_zero<<<(N_NODES + 512 + 255) / 256, 256, 0, stream>>>(P.cnt);
  k_hist<<<(N_EDGES + 255) / 256, 256, 0, stream>>>(P.ei, P.cnt);
  k_scan1<<<NB_SCAN, 256, 0, stream>>>(P.cnt, P.offs, P.bsum);
  k_scan2<<<1, 256, 0, stream>>>(P.bsum);
  k_scan3<<<NB_SCAN, 256, 0, stream>>>(P.offs, P.bsum, P.cursor);
  k_scatter<<<(N_EDGES + 255) / 256, 256, 0, stream>>>(P);
  k_gather<<<(N_NODES + 255) / 256, 256, 0, stream>>>(P);
  k_fc<<<512, 128, 0, stream>>>(P);
  k_mfma<0><<<NTILES, 256, 0, stream>>>(P);
  k_mfma<1><<<NTILES, 256, 0, stream>>>(P);
}